// Round 5
// baseline (473.669 us; speedup 1.0000x reference)
//
#include <hip/hip_runtime.h>
#include <hip/hip_bf16.h>
#include <math.h>

// MultiHeadAttention  B=4, T=2048, D=512, H=8, DH=64, fp32 in/out.
// R5 (= R4 with compile fix): swapped-QK^T attention (lane-local softmax,
// 2 shuffles/tile, defer-max, exp2 domain via __builtin_amdgcn_exp2f),
// 32x32 register-double-buffered bf16 projections, O-projection via
// 3-term split-bf16 (near-fp32-exact) K=1536 GEMM.

#define TB 2048
#define DD 512
#define NH 8
#define DH 64

typedef short bf16x8 __attribute__((ext_vector_type(8)));
typedef float f32x4 __attribute__((ext_vector_type(4)));
typedef ushort u16x8 __attribute__((ext_vector_type(8)));

static __device__ __forceinline__ ushort f2bf(float x) {
  __hip_bfloat16 h = __float2bfloat16(x);
  return *reinterpret_cast<ushort*>(&h);
}
static __device__ __forceinline__ float bf2f(ushort u) {
  unsigned int v = ((unsigned int)u) << 16;
  return __uint_as_float(v);
}
static __device__ __forceinline__ float fast_exp2(float x) {
  return __builtin_amdgcn_exp2f(x);  // v_exp_f32: D = 2^S0
}

// ---------------------------------------------------------------------------
// Mask canonicalization (verified R1-R3). Output: float bias 0 / -inf.
__global__ void mask_detect_kernel(const unsigned char* __restrict__ m,
                                   int* __restrict__ mode) {
  __shared__ int c1, c2;
  if (threadIdx.x == 0) { c1 = 0; c2 = 0; }
  __syncthreads();
  int l1 = 0, l2 = 0;
  for (int i = threadIdx.x; i < 8192; i += blockDim.x) {
    int ph = i & 3;
    unsigned char v = m[i];
    if (ph == 1 && v) l1++;
    if (ph == 2 && v) l2++;
  }
  if (l1) atomicAdd(&c1, l1);
  if (l2) atomicAdd(&c2, l2);
  __syncthreads();
  if (threadIdx.x == 0) *mode = (c1 > 0) ? 0 : ((c2 > 0) ? 1 : 2);
}

__global__ void mask_build_kernel(const void* __restrict__ m,
                                  const int* __restrict__ mode,
                                  float* __restrict__ out) {
  int i = blockIdx.x * blockDim.x + threadIdx.x;
  int md = *mode;
  int v;
  if (md == 0)      v = ((const unsigned char*)m)[i] != 0;
  else if (md == 1) v = ((const float*)m)[i] != 0.0f;
  else              v = ((const int*)m)[i] != 0;
  out[i] = v ? 0.0f : -INFINITY;
}

// ---------------------------------------------------------------------------
// fp32 -> bf16 bulk convert.
__global__ __launch_bounds__(256) void cvt_kernel(const float* __restrict__ in,
                                                  ushort* __restrict__ out) {
  size_t i = ((size_t)blockIdx.x * 256 + threadIdx.x) * 8;
  float4 a = *(const float4*)&in[i];
  float4 b = *(const float4*)&in[i + 4];
  u16x8 o;
  o[0] = f2bf(a.x); o[1] = f2bf(a.y); o[2] = f2bf(a.z); o[3] = f2bf(a.w);
  o[4] = f2bf(b.x); o[5] = f2bf(b.y); o[6] = f2bf(b.z); o[7] = f2bf(b.w);
  *(u16x8*)&out[i] = o;
}

// ---------------------------------------------------------------------------
// W [K][N] f32 -> Wt [N][K] bf16 (for Q/K/V projections).
__global__ __launch_bounds__(256) void wtrans_kernel(const float* __restrict__ W,
                                                     ushort* __restrict__ Wt) {
  __shared__ ushort t[64][68];
  const int bn = blockIdx.x << 6, bk = blockIdx.y << 6;
  const int tx = threadIdx.x & 15, ty = threadIdx.x >> 4;
#pragma unroll
  for (int rr = 0; rr < 64; rr += 16) {
    float4 v = *(const float4*)&W[(size_t)(bk + rr + ty) * DD + bn + (tx << 2)];
    t[(tx << 2) + 0][rr + ty] = f2bf(v.x);
    t[(tx << 2) + 1][rr + ty] = f2bf(v.y);
    t[(tx << 2) + 2][rr + ty] = f2bf(v.z);
    t[(tx << 2) + 3][rr + ty] = f2bf(v.w);
  }
  __syncthreads();
#pragma unroll
  for (int rr = 0; rr < 64; rr += 16) {
    ushort4 o;
    o.x = t[rr + ty][(tx << 2) + 0];
    o.y = t[rr + ty][(tx << 2) + 1];
    o.z = t[rr + ty][(tx << 2) + 2];
    o.w = t[rr + ty][(tx << 2) + 3];
    *(ushort4*)&Wt[(size_t)(bn + rr + ty) * DD + bk + (tx << 2)] = o;
  }
}

// ---------------------------------------------------------------------------
// Wo [K][N] f32 -> Wt' [N][1536]: sections [Whi | Whi | Wlo] (split-bf16).
__global__ __launch_bounds__(256) void wtrans_split_kernel(
    const float* __restrict__ W, ushort* __restrict__ Wt) {
  __shared__ ushort thi[64][68];
  __shared__ ushort tlo[64][68];
  const int bn = blockIdx.x << 6, bk = blockIdx.y << 6;
  const int tx = threadIdx.x & 15, ty = threadIdx.x >> 4;
#pragma unroll
  for (int rr = 0; rr < 64; rr += 16) {
    float4 v = *(const float4*)&W[(size_t)(bk + rr + ty) * DD + bn + (tx << 2)];
    float vv[4] = {v.x, v.y, v.z, v.w};
#pragma unroll
    for (int c = 0; c < 4; ++c) {
      ushort hi = f2bf(vv[c]);
      ushort lo = f2bf(vv[c] - bf2f(hi));
      thi[(tx << 2) + c][rr + ty] = hi;
      tlo[(tx << 2) + c][rr + ty] = lo;
    }
  }
  __syncthreads();
#pragma unroll
  for (int rr = 0; rr < 64; rr += 16) {
    ushort4 h4, l4;
    h4.x = thi[rr + ty][(tx << 2) + 0];
    h4.y = thi[rr + ty][(tx << 2) + 1];
    h4.z = thi[rr + ty][(tx << 2) + 2];
    h4.w = thi[rr + ty][(tx << 2) + 3];
    l4.x = tlo[rr + ty][(tx << 2) + 0];
    l4.y = tlo[rr + ty][(tx << 2) + 1];
    l4.z = tlo[rr + ty][(tx << 2) + 2];
    l4.w = tlo[rr + ty][(tx << 2) + 3];
    size_t rowb = (size_t)(bn + rr + ty) * 1536;
    *(ushort4*)&Wt[rowb + bk + (tx << 2)] = h4;         // sec0: Whi
    *(ushort4*)&Wt[rowb + 512 + bk + (tx << 2)] = h4;   // sec1: Whi
    *(ushort4*)&Wt[rowb + 1024 + bk + (tx << 2)] = l4;  // sec2: Wlo
  }
}

// ---------------------------------------------------------------------------
// bf16 MFMA GEMM, one wave/block, 32x32 tile, register-double-buffered K.
// A [M][K] bf16, Wt [N][K] bf16, bias f32[512]. K = 512 or 1536.
// MODE 0: bf16 heads [B,H,T,DH]; MODE 2: bf16 V^T [B,H,DH,T]; MODE 1: f32 flat.
template <int MODE>
__global__ __launch_bounds__(64) void proj32_kernel(
    const ushort* __restrict__ A, const ushort* __restrict__ Wt,
    const float* __restrict__ bias, void* __restrict__ Yv, float scale, int K) {
  const int lane = threadIdx.x, llo = lane & 15, lhi = lane >> 4;
  const int m0 = blockIdx.x << 5, n0 = blockIdx.y << 5;
  const ushort* Ar0 = A + (size_t)(m0 + llo) * K;
  const ushort* Ar1 = Ar0 + (size_t)16 * K;
  const ushort* Br0 = Wt + (size_t)(n0 + llo) * K;
  const ushort* Br1 = Br0 + (size_t)16 * K;

  f32x4 acc[2][2];
#pragma unroll
  for (int i = 0; i < 2; ++i)
#pragma unroll
    for (int j = 0; j < 2; ++j) acc[i][j] = (f32x4){0.f, 0.f, 0.f, 0.f};

  int ko = lhi * 8;
  bf16x8 a0 = *(const bf16x8*)&Ar0[ko];
  bf16x8 a1 = *(const bf16x8*)&Ar1[ko];
  bf16x8 b0 = *(const bf16x8*)&Br0[ko];
  bf16x8 b1 = *(const bf16x8*)&Br1[ko];

  const int nsteps = K >> 5;
  for (int ks = 1; ks <= nsteps; ++ks) {
    const int kn = (ks < nsteps ? ks * 32 : 0) + lhi * 8;
    bf16x8 a0n = *(const bf16x8*)&Ar0[kn];
    bf16x8 a1n = *(const bf16x8*)&Ar1[kn];
    bf16x8 b0n = *(const bf16x8*)&Br0[kn];
    bf16x8 b1n = *(const bf16x8*)&Br1[kn];
    acc[0][0] = __builtin_amdgcn_mfma_f32_16x16x32_bf16(a0, b0, acc[0][0], 0, 0, 0);
    acc[0][1] = __builtin_amdgcn_mfma_f32_16x16x32_bf16(a0, b1, acc[0][1], 0, 0, 0);
    acc[1][0] = __builtin_amdgcn_mfma_f32_16x16x32_bf16(a1, b0, acc[1][0], 0, 0, 0);
    acc[1][1] = __builtin_amdgcn_mfma_f32_16x16x32_bf16(a1, b1, acc[1][1], 0, 0, 0);
    a0 = a0n; a1 = a1n; b0 = b0n; b1 = b1n;
  }

  float bb[2];
#pragma unroll
  for (int ni = 0; ni < 2; ++ni) bb[ni] = bias[n0 + ni * 16 + llo];

  if (MODE == 1) {
    float* Yf = (float*)Yv;
#pragma unroll
    for (int mi = 0; mi < 2; ++mi)
#pragma unroll
      for (int ni = 0; ni < 2; ++ni)
#pragma unroll
        for (int r = 0; r < 4; ++r) {
          int row = m0 + mi * 16 + lhi * 4 + r;
          int col = n0 + ni * 16 + llo;
          Yf[(size_t)row * DD + col] = acc[mi][ni][r] + bb[ni];
        }
  } else if (MODE == 0) {
    ushort* Yb = (ushort*)Yv;
#pragma unroll
    for (int mi = 0; mi < 2; ++mi)
#pragma unroll
      for (int ni = 0; ni < 2; ++ni) {
        int col = n0 + ni * 16 + llo;
        int h = col >> 6, dh = col & (DH - 1);
#pragma unroll
        for (int r = 0; r < 4; ++r) {
          int row = m0 + mi * 16 + lhi * 4 + r;
          int b = row >> 11, t = row & (TB - 1);
          Yb[((((size_t)b * NH + h) * TB) + t) * DH + dh] =
              f2bf((acc[mi][ni][r] + bb[ni]) * scale);
        }
      }
  } else {  // MODE 2: V^T [B,H,DH,T]
    ushort* Yb = (ushort*)Yv;
#pragma unroll
    for (int mi = 0; mi < 2; ++mi)
#pragma unroll
      for (int ni = 0; ni < 2; ++ni) {
        int col = n0 + ni * 16 + llo;
        int h = col >> 6, dh = col & (DH - 1);
#pragma unroll
        for (int r = 0; r < 4; ++r) {
          int row = m0 + mi * 16 + lhi * 4 + r;
          int b = row >> 11, t = row & (TB - 1);
          Yb[(((size_t)b * NH + h) * DH + dh) * TB + t] =
              f2bf((acc[mi][ni][r] + bb[ni]) * scale);
        }
      }
  }
}

// ---------------------------------------------------------------------------
// Swapped-QK^T bf16 MFMA flash attention.
// S^T = mfma(A=K, B=Q): lane owns q-row llo; keys nt*16+lhi*4+r in regs.
// Softmax: in-lane trees + 2 shuffles (xor16/xor32). Defer-max thr=8 (log2).
// P -> per-wave LDS (4x ds_write_b64) -> A-frag (2x ds_read_b128).
// PV = mfma(A=P, B=V^T). Epilogue writes split-bf16 A' = [hi|lo|hi] rows.
__global__ __launch_bounds__(256) void attn_mfma_kernel(
    const ushort* __restrict__ Qh,  // [BH][T][DH], scaled 0.125*log2e
    const ushort* __restrict__ Kh,  // [BH][T][DH]
    const ushort* __restrict__ Vt,  // [BH][DH][T]
    const float* __restrict__ mbias,  // [B][T] 0 / -inf
    ushort* __restrict__ Ap) {        // A' [8192][1536]
  __shared__ __align__(16) ushort Plds[4][16][72];

  const int tid = threadIdx.x;
  const int w = tid >> 6, lane = tid & 63;
  const int lhi = lane >> 4, llo = lane & 15;

  const int bid = blockIdx.x;
  const int j = bid >> 3;
  const int bh = (bid & 7) + ((j >> 5) << 3);  // same-bh blocks -> same XCD
  const int qt = j & 31;
  const int b = bh >> 3, h = bh & 7;
  const int q0 = qt << 6;

  const ushort* Qb = Qh + ((size_t)bh * TB + q0 + w * 16) * DH;
  const ushort* Kb = Kh + (size_t)bh * TB * DH;
  const ushort* Vb = Vt + (size_t)bh * DH * TB;
  const float* mb = mbias + b * TB;
  ushort* pl = &Plds[w][0][0];  // [16][72]

  // Q as B-fragment: col = llo = q-row, k = lhi*8 (+32 for chunk 1)
  bf16x8 qa0 = *(const bf16x8*)&Qb[llo * DH + lhi * 8];
  bf16x8 qa1 = *(const bf16x8*)&Qb[llo * DH + 32 + lhi * 8];

  f32x4 oacc[4];  // oacc[nt][r]: row q=lhi*4+r (of S^T cols), col dh=nt*16+llo
#pragma unroll
  for (int nt = 0; nt < 4; ++nt) oacc[nt] = (f32x4){0.f, 0.f, 0.f, 0.f};
  float m = -INFINITY, l = 0.f;

  // K prologue (A-frag: row = key = nt*16+llo)
  bf16x8 kf[4][2];
#pragma unroll
  for (int nt = 0; nt < 4; ++nt) {
    const ushort* kr = &Kb[(size_t)(nt * 16 + llo) * DH + lhi * 8];
    kf[nt][0] = *(const bf16x8*)kr;
    kf[nt][1] = *(const bf16x8*)(kr + 32);
  }

  for (int kt = 0; kt < TB; kt += 64) {
    // early-issue V fragments + mask bias for this tile
    bf16x8 vf[2][4];
#pragma unroll
    for (int kc = 0; kc < 2; ++kc)
#pragma unroll
      for (int nt = 0; nt < 4; ++nt)
        vf[kc][nt] = *(const bf16x8*)
            &Vb[(size_t)(nt * 16 + llo) * TB + kt + kc * 32 + lhi * 8];
    float4 mb4[4];
#pragma unroll
    for (int nt = 0; nt < 4; ++nt)
      mb4[nt] = *(const float4*)&mb[kt + nt * 16 + lhi * 4];

    // S^T = K Q^T
    f32x4 s[4];
    __builtin_amdgcn_s_setprio(1);
#pragma unroll
    for (int nt = 0; nt < 4; ++nt) {
      s[nt] = (f32x4){0.f, 0.f, 0.f, 0.f};
      s[nt] = __builtin_amdgcn_mfma_f32_16x16x32_bf16(kf[nt][0], qa0, s[nt], 0, 0, 0);
      s[nt] = __builtin_amdgcn_mfma_f32_16x16x32_bf16(kf[nt][1], qa1, s[nt], 0, 0, 0);
    }
    __builtin_amdgcn_s_setprio(0);

    // prefetch next K tile (wraps; harmless)
    const int ktn = (kt + 64) & (TB - 1);
#pragma unroll
    for (int nt = 0; nt < 4; ++nt) {
      const ushort* kr = &Kb[(size_t)(ktn + nt * 16 + llo) * DH + lhi * 8];
      kf[nt][0] = *(const bf16x8*)kr;
      kf[nt][1] = *(const bf16x8*)(kr + 32);
    }

    // mask bias add (-inf for masked keys; key = nt*16 + lhi*4 + r)
#pragma unroll
    for (int nt = 0; nt < 4; ++nt) {
      s[nt][0] += mb4[nt].x;
      s[nt][1] += mb4[nt].y;
      s[nt][2] += mb4[nt].z;
      s[nt][3] += mb4[nt].w;
    }

    // in-lane max over 16 keys, then across the 4 lhi lanes of this q-row
    float mx[4];
#pragma unroll
    for (int nt = 0; nt < 4; ++nt)
      mx[nt] = fmaxf(fmaxf(s[nt][0], s[nt][1]), fmaxf(s[nt][2], s[nt][3]));
    float pmax = fmaxf(fmaxf(mx[0], mx[1]), fmaxf(mx[2], mx[3]));
    pmax = fmaxf(pmax, __shfl_xor(pmax, 16));
    pmax = fmaxf(pmax, __shfl_xor(pmax, 32));

    // defer-max: rescale only if some row grew past m+8 (log2 units)
    if (__any(pmax > m + 8.f)) {
      float newm = fmaxf(m, pmax);
      float alpha = fast_exp2(m - newm);
      if (__any(newm == -INFINITY)) {
        if (newm == -INFINITY) alpha = 0.f;  // dead row (all keys masked)
      }
      float al[4];
#pragma unroll
      for (int r = 0; r < 4; ++r) al[r] = __shfl(alpha, lhi * 4 + r);
#pragma unroll
      for (int nt = 0; nt < 4; ++nt) {
        oacc[nt][0] *= al[0];
        oacc[nt][1] *= al[1];
        oacc[nt][2] *= al[2];
        oacc[nt][3] *= al[3];
      }
      l *= alpha;
      m = newm;
    }

    // p = exp2(s - m), in place
#pragma unroll
    for (int nt = 0; nt < 4; ++nt)
#pragma unroll
      for (int r = 0; r < 4; ++r) s[nt][r] = fast_exp2(s[nt][r] - m);
    float sm[4];
#pragma unroll
    for (int nt = 0; nt < 4; ++nt)
      sm[nt] = (s[nt][0] + s[nt][1]) + (s[nt][2] + s[nt][3]);
    float rsum = (sm[0] + sm[1]) + (sm[2] + sm[3]);
    if (__any(m == -INFINITY)) {  // dead rows: exp2(-inf - -inf)=nan scrub
      if (m == -INFINITY) {
        rsum = 0.f;
#pragma unroll
        for (int nt = 0; nt < 4; ++nt) s[nt] = (f32x4){0.f, 0.f, 0.f, 0.f};
      }
    }
    rsum += __shfl_xor(rsum, 16);
    rsum += __shfl_xor(rsum, 32);
    l += rsum;

    // P -> LDS: lane writes 4 consecutive keys per nt for q-row llo
#pragma unroll
    for (int nt = 0; nt < 4; ++nt) {
      ushort4 pk;
      pk.x = f2bf(s[nt][0]);
      pk.y = f2bf(s[nt][1]);
      pk.z = f2bf(s[nt][2]);
      pk.w = f2bf(s[nt][3]);
      *(ushort4*)&pl[llo * 72 + nt * 16 + lhi * 4] = pk;
    }

    // O += P V  (A-frag: row=llo=q-row, k=keys kc*32+lhi*8..+7)
    __builtin_amdgcn_s_setprio(1);
#pragma unroll
    for (int kc = 0; kc < 2; ++kc) {
      bf16x8 pa = *(const bf16x8*)&pl[llo * 72 + kc * 32 + lhi * 8];
#pragma unroll
      for (int nt = 0; nt < 4; ++nt)
        oacc[nt] = __builtin_amdgcn_mfma_f32_16x16x32_bf16(pa, vf[kc][nt], oacc[nt], 0, 0, 0);
    }
    __builtin_amdgcn_s_setprio(0);
  }

  // epilogue: normalize rows, write split-bf16 A' = [hi | lo | hi]
  float linv = (l > 0.f) ? 1.f / l : 0.f;
  float il[4];
#pragma unroll
  for (int r = 0; r < 4; ++r) il[r] = __shfl(linv, lhi * 4 + r);
  const int t0 = q0 + w * 16 + lhi * 4;
#pragma unroll
  for (int r = 0; r < 4; ++r) {
    size_t rowb = (size_t)(b * TB + t0 + r) * 1536;
#pragma unroll
    for (int nt = 0; nt < 4; ++nt) {
      float o = oacc[nt][r] * il[r];
      ushort hi = f2bf(o);
      ushort lo = f2bf(o - bf2f(hi));
      int c = h * DH + nt * 16 + llo;
      Ap[rowb + c] = hi;
      Ap[rowb + 512 + c] = lo;
      Ap[rowb + 1024 + c] = hi;
    }
  }
}

// ---------------------------------------------------------------------------
extern "C" void kernel_launch(void* const* d_in, const int* in_sizes, int n_in,
                              void* d_out, int out_size, void* d_ws,
                              size_t ws_size, hipStream_t stream) {
  (void)in_sizes; (void)n_in; (void)out_size; (void)ws_size;
  const float* q = (const float*)d_in[0];
  const float* k = (const float*)d_in[1];
  const float* v = (const float*)d_in[2];
  const void* pm = d_in[3];
  const float* Wq = (const float*)d_in[4];
  const float* bq = (const float*)d_in[5];
  const float* Wk = (const float*)d_in[6];
  const float* bk = (const float*)d_in[7];
  const float* Wv = (const float*)d_in[8];
  const float* bv = (const float*)d_in[9];
  const float* Wo = (const float*)d_in[10];
  const float* bo = (const float*)d_in[11];

  char* ws = (char*)d_ws;
  const size_t MB = (size_t)1 << 20;
  // [0,24MB): bf16 inputs (dead after projs) -> reused as A' (24MB, attn out)
  ushort* Qb16 = (ushort*)(ws);
  ushort* Kb16 = (ushort*)(ws + 8 * MB);
  ushort* Vb16 = (ushort*)(ws + 16 * MB);
  ushort* Ap = (ushort*)(ws);  // 8192*1536*2 = 24MB exactly
  // [24,25.5MB): Q/K/V weight transposes (dead after projs)
  ushort* Wqt = (ushort*)(ws + 24 * MB);
  ushort* Wkt = (ushort*)(ws + 24 * MB + 512 * 1024);
  ushort* Wvt = (ushort*)(ws + 25 * MB);
  // [26,27.5MB): split O-weight (live until oproj)
  ushort* Wot = (ushort*)(ws + 26 * MB);
  // [32,56MB): projected heads (live through attention)
  ushort* Qh = (ushort*)(ws + 32 * MB);
  ushort* Kh = (ushort*)(ws + 40 * MB);
  ushort* Vt = (ushort*)(ws + 48 * MB);
  float* mbias = (float*)(ws + 56 * MB);
  int* mode = (int*)(ws + 56 * MB + 40960);

  mask_detect_kernel<<<1, 256, 0, stream>>>((const unsigned char*)pm, mode);
  mask_build_kernel<<<32, 256, 0, stream>>>(pm, mode, mbias);

  cvt_kernel<<<2048, 256, 0, stream>>>(q, Qb16);
  cvt_kernel<<<2048, 256, 0, stream>>>(k, Kb16);
  cvt_kernel<<<2048, 256, 0, stream>>>(v, Vb16);
  wtrans_kernel<<<dim3(8, 8), 256, 0, stream>>>(Wq, Wqt);
  wtrans_kernel<<<dim3(8, 8), 256, 0, stream>>>(Wk, Wkt);
  wtrans_kernel<<<dim3(8, 8), 256, 0, stream>>>(Wv, Wvt);
  wtrans_split_kernel<<<dim3(8, 8), 256, 0, stream>>>(Wo, Wot);

  // Q scale folds 1/sqrt(64) * log2(e) for the exp2-domain softmax
  const float qscale = 0.125f * 1.4426950408889634f;
  dim3 pg(256, 16);  // 4096 one-wave blocks
  proj32_kernel<0><<<pg, 64, 0, stream>>>(Qb16, Wqt, bq, Qh, qscale, DD);
  proj32_kernel<0><<<pg, 64, 0, stream>>>(Kb16, Wkt, bk, Kh, 1.0f, DD);
  proj32_kernel<2><<<pg, 64, 0, stream>>>(Vb16, Wvt, bv, Vt, 1.0f, DD);

  attn_mfma_kernel<<<1024, 256, 0, stream>>>(Qh, Kh, Vt, mbias, Ap);

  proj32_kernel<1><<<pg, 64, 0, stream>>>(Ap, Wot, bo, d_out, 1.0f, 1536);
}

// Round 6
// 464.594 us; speedup vs baseline: 1.0195x; 1.0195x over previous
//
#include <hip/hip_runtime.h>
#include <hip/hip_bf16.h>
#include <math.h>

// MultiHeadAttention  B=4, T=2048, D=512, H=8, DH=64, fp32 in/out.
// R6: in-block split-K attention (4 waves x 512 keys, LDS merge), 4096 blocks;
// fused QKV projection + O-projection with lookahead-2 register pipelines.

#define TB 2048
#define DD 512
#define NH 8
#define DH 64

typedef short bf16x8 __attribute__((ext_vector_type(8)));
typedef float f32x4 __attribute__((ext_vector_type(4)));
typedef ushort u16x8 __attribute__((ext_vector_type(8)));

static __device__ __forceinline__ ushort f2bf(float x) {
  __hip_bfloat16 h = __float2bfloat16(x);
  return *reinterpret_cast<ushort*>(&h);
}
static __device__ __forceinline__ float bf2f(ushort u) {
  unsigned int v = ((unsigned int)u) << 16;
  return __uint_as_float(v);
}
static __device__ __forceinline__ float fast_exp2(float x) {
  return __builtin_amdgcn_exp2f(x);  // v_exp_f32: D = 2^S0
}

// ---------------------------------------------------------------------------
// Mask canonicalization (verified R1-R5). Output: float bias 0 / -inf.
__global__ void mask_detect_kernel(const unsigned char* __restrict__ m,
                                   int* __restrict__ mode) {
  __shared__ int c1, c2;
  if (threadIdx.x == 0) { c1 = 0; c2 = 0; }
  __syncthreads();
  int l1 = 0, l2 = 0;
  for (int i = threadIdx.x; i < 8192; i += blockDim.x) {
    int ph = i & 3;
    unsigned char v = m[i];
    if (ph == 1 && v) l1++;
    if (ph == 2 && v) l2++;
  }
  if (l1) atomicAdd(&c1, l1);
  if (l2) atomicAdd(&c2, l2);
  __syncthreads();
  if (threadIdx.x == 0) *mode = (c1 > 0) ? 0 : ((c2 > 0) ? 1 : 2);
}

__global__ void mask_build_kernel(const void* __restrict__ m,
                                  const int* __restrict__ mode,
                                  float* __restrict__ out) {
  int i = blockIdx.x * blockDim.x + threadIdx.x;
  int md = *mode;
  int v;
  if (md == 0)      v = ((const unsigned char*)m)[i] != 0;
  else if (md == 1) v = ((const float*)m)[i] != 0.0f;
  else              v = ((const int*)m)[i] != 0;
  out[i] = v ? 0.0f : -INFINITY;
}

// ---------------------------------------------------------------------------
// fp32 -> bf16 bulk convert.
__global__ __launch_bounds__(256) void cvt_kernel(const float* __restrict__ in,
                                                  ushort* __restrict__ out) {
  size_t i = ((size_t)blockIdx.x * 256 + threadIdx.x) * 8;
  float4 a = *(const float4*)&in[i];
  float4 b = *(const float4*)&in[i + 4];
  u16x8 o;
  o[0] = f2bf(a.x); o[1] = f2bf(a.y); o[2] = f2bf(a.z); o[3] = f2bf(a.w);
  o[4] = f2bf(b.x); o[5] = f2bf(b.y); o[6] = f2bf(b.z); o[7] = f2bf(b.w);
  *(u16x8*)&out[i] = o;
}

// ---------------------------------------------------------------------------
// W [K][N] f32 -> Wt [N][K] bf16.
__global__ __launch_bounds__(256) void wtrans_kernel(const float* __restrict__ W,
                                                     ushort* __restrict__ Wt) {
  __shared__ ushort t[64][68];
  const int bn = blockIdx.x << 6, bk = blockIdx.y << 6;
  const int tx = threadIdx.x & 15, ty = threadIdx.x >> 4;
#pragma unroll
  for (int rr = 0; rr < 64; rr += 16) {
    float4 v = *(const float4*)&W[(size_t)(bk + rr + ty) * DD + bn + (tx << 2)];
    t[(tx << 2) + 0][rr + ty] = f2bf(v.x);
    t[(tx << 2) + 1][rr + ty] = f2bf(v.y);
    t[(tx << 2) + 2][rr + ty] = f2bf(v.z);
    t[(tx << 2) + 3][rr + ty] = f2bf(v.w);
  }
  __syncthreads();
#pragma unroll
  for (int rr = 0; rr < 64; rr += 16) {
    ushort4 o;
    o.x = t[rr + ty][(tx << 2) + 0];
    o.y = t[rr + ty][(tx << 2) + 1];
    o.z = t[rr + ty][(tx << 2) + 2];
    o.w = t[rr + ty][(tx << 2) + 3];
    *(ushort4*)&Wt[(size_t)(bn + rr + ty) * DD + bk + (tx << 2)] = o;
  }
}

// ---------------------------------------------------------------------------
// Wo [K][N] f32 -> Wt' [N][1536]: sections [Whi | Whi | Wlo] (split-bf16).
__global__ __launch_bounds__(256) void wtrans_split_kernel(
    const float* __restrict__ W, ushort* __restrict__ Wt) {
  __shared__ ushort thi[64][68];
  __shared__ ushort tlo[64][68];
  const int bn = blockIdx.x << 6, bk = blockIdx.y << 6;
  const int tx = threadIdx.x & 15, ty = threadIdx.x >> 4;
#pragma unroll
  for (int rr = 0; rr < 64; rr += 16) {
    float4 v = *(const float4*)&W[(size_t)(bk + rr + ty) * DD + bn + (tx << 2)];
    float vv[4] = {v.x, v.y, v.z, v.w};
#pragma unroll
    for (int c = 0; c < 4; ++c) {
      ushort hi = f2bf(vv[c]);
      ushort lo = f2bf(vv[c] - bf2f(hi));
      thi[(tx << 2) + c][rr + ty] = hi;
      tlo[(tx << 2) + c][rr + ty] = lo;
    }
  }
  __syncthreads();
#pragma unroll
  for (int rr = 0; rr < 64; rr += 16) {
    ushort4 h4, l4;
    h4.x = thi[rr + ty][(tx << 2) + 0];
    h4.y = thi[rr + ty][(tx << 2) + 1];
    h4.z = thi[rr + ty][(tx << 2) + 2];
    h4.w = thi[rr + ty][(tx << 2) + 3];
    l4.x = tlo[rr + ty][(tx << 2) + 0];
    l4.y = tlo[rr + ty][(tx << 2) + 1];
    l4.z = tlo[rr + ty][(tx << 2) + 2];
    l4.w = tlo[rr + ty][(tx << 2) + 3];
    size_t rowb = (size_t)(bn + rr + ty) * 1536;
    *(ushort4*)&Wt[rowb + bk + (tx << 2)] = h4;         // sec0: Whi
    *(ushort4*)&Wt[rowb + 512 + bk + (tx << 2)] = h4;   // sec1: Whi
    *(ushort4*)&Wt[rowb + 1024 + bk + (tx << 2)] = l4;  // sec2: Wlo
  }
}

// ---------------------------------------------------------------------------
// Fused QKV projection: one wave/block, 32x32 tile, lookahead-2 pipeline.
// grid (256, 48): blockIdx.y selects section (0=Q,1=K,2=V) and n-tile.
__global__ __launch_bounds__(64) void projqkv_kernel(
    const ushort* __restrict__ Qx, const ushort* __restrict__ Kx,
    const ushort* __restrict__ Vx, const ushort* __restrict__ Wall,
    const float* __restrict__ bq, const float* __restrict__ bk,
    const float* __restrict__ bv, ushort* __restrict__ Yall, float qscale) {
  const int lane = threadIdx.x, llo = lane & 15, lhi = lane >> 4;
  const int m0 = blockIdx.x << 5;
  const int ny = blockIdx.y;
  const int sec = ny >> 4;          // 0=Q, 1=K, 2=V
  const int n0 = (ny << 5) & 511;   // within-section col base

  const ushort* A = (sec == 0) ? Qx : (sec == 1) ? Kx : Vx;
  const float* bias = (sec == 0) ? bq : (sec == 1) ? bk : bv;
  const float scale = (sec == 0) ? qscale : 1.0f;

  const ushort* Ar0 = A + (size_t)(m0 + llo) * DD;
  const ushort* Ar1 = Ar0 + (size_t)16 * DD;
  const ushort* Br0 = Wall + (size_t)(ny * 32 + llo) * DD;
  const ushort* Br1 = Br0 + (size_t)16 * DD;

  f32x4 a00 = {0.f,0.f,0.f,0.f}, a01 = a00, a10 = a00, a11 = a00;

  const int koff = lhi * 8;
  // lookahead-2 prologue: sets A (k-step 0) and B (k-step 1)
  bf16x8 aA0 = *(const bf16x8*)&Ar0[koff];
  bf16x8 aA1 = *(const bf16x8*)&Ar1[koff];
  bf16x8 bA0 = *(const bf16x8*)&Br0[koff];
  bf16x8 bA1 = *(const bf16x8*)&Br1[koff];
  bf16x8 aB0 = *(const bf16x8*)&Ar0[32 + koff];
  bf16x8 aB1 = *(const bf16x8*)&Ar1[32 + koff];
  bf16x8 bB0 = *(const bf16x8*)&Br0[32 + koff];
  bf16x8 bB1 = *(const bf16x8*)&Br1[32 + koff];

  const int nsteps = DD >> 5;  // 16
#pragma unroll 2
  for (int ks = 0; ks < nsteps; ks += 2) {
    const int k2 = ((ks + 2 < nsteps) ? (ks + 2) * 32 : 0) + koff;
    const int k3 = ((ks + 3 < nsteps) ? (ks + 3) * 32 : 32) + koff;
    a00 = __builtin_amdgcn_mfma_f32_16x16x32_bf16(aA0, bA0, a00, 0, 0, 0);
    a01 = __builtin_amdgcn_mfma_f32_16x16x32_bf16(aA0, bA1, a01, 0, 0, 0);
    a10 = __builtin_amdgcn_mfma_f32_16x16x32_bf16(aA1, bA0, a10, 0, 0, 0);
    a11 = __builtin_amdgcn_mfma_f32_16x16x32_bf16(aA1, bA1, a11, 0, 0, 0);
    aA0 = *(const bf16x8*)&Ar0[k2];
    aA1 = *(const bf16x8*)&Ar1[k2];
    bA0 = *(const bf16x8*)&Br0[k2];
    bA1 = *(const bf16x8*)&Br1[k2];
    a00 = __builtin_amdgcn_mfma_f32_16x16x32_bf16(aB0, bB0, a00, 0, 0, 0);
    a01 = __builtin_amdgcn_mfma_f32_16x16x32_bf16(aB0, bB1, a01, 0, 0, 0);
    a10 = __builtin_amdgcn_mfma_f32_16x16x32_bf16(aB1, bB0, a10, 0, 0, 0);
    a11 = __builtin_amdgcn_mfma_f32_16x16x32_bf16(aB1, bB1, a11, 0, 0, 0);
    aB0 = *(const bf16x8*)&Ar0[k3];
    aB1 = *(const bf16x8*)&Ar1[k3];
    bB0 = *(const bf16x8*)&Br0[k3];
    bB1 = *(const bf16x8*)&Br1[k3];
  }

  float bb[2];
#pragma unroll
  for (int ni = 0; ni < 2; ++ni) bb[ni] = bias[n0 + ni * 16 + llo];

  ushort* Yb = Yall + (size_t)sec * ((size_t)4 << 20);  // 8MB sections
  const f32x4 accs[2][2] = {{a00, a01}, {a10, a11}};
  if (sec < 2) {  // [B,H,T,DH]
#pragma unroll
    for (int mi = 0; mi < 2; ++mi)
#pragma unroll
      for (int ni = 0; ni < 2; ++ni) {
        int col = n0 + ni * 16 + llo;
        int h = col >> 6, dh = col & (DH - 1);
#pragma unroll
        for (int r = 0; r < 4; ++r) {
          int row = m0 + mi * 16 + lhi * 4 + r;
          int b = row >> 11, t = row & (TB - 1);
          Yb[((((size_t)b * NH + h) * TB) + t) * DH + dh] =
              f2bf((accs[mi][ni][r] + bb[ni]) * scale);
        }
      }
  } else {  // V^T [B,H,DH,T]
#pragma unroll
    for (int mi = 0; mi < 2; ++mi)
#pragma unroll
      for (int ni = 0; ni < 2; ++ni) {
        int col = n0 + ni * 16 + llo;
        int h = col >> 6, dh = col & (DH - 1);
#pragma unroll
        for (int r = 0; r < 4; ++r) {
          int row = m0 + mi * 16 + lhi * 4 + r;
          int b = row >> 11, t = row & (TB - 1);
          Yb[(((size_t)b * NH + h) * DH + dh) * TB + t] =
              f2bf((accs[mi][ni][r] + bb[ni]) * scale);
        }
      }
  }
}

// ---------------------------------------------------------------------------
// O-projection: A' [8192][1536] split-bf16 @ Wot [512][1536] -> f32 + bias.
// One wave/block, 32x32 tile, lookahead-2.
__global__ __launch_bounds__(64) void projo_kernel(
    const ushort* __restrict__ A, const ushort* __restrict__ Wt,
    const float* __restrict__ bias, float* __restrict__ Y) {
  const int lane = threadIdx.x, llo = lane & 15, lhi = lane >> 4;
  const int m0 = blockIdx.x << 5, n0 = blockIdx.y << 5;
  const int K = 1536;
  const ushort* Ar0 = A + (size_t)(m0 + llo) * K;
  const ushort* Ar1 = Ar0 + (size_t)16 * K;
  const ushort* Br0 = Wt + (size_t)(n0 + llo) * K;
  const ushort* Br1 = Br0 + (size_t)16 * K;

  f32x4 a00 = {0.f,0.f,0.f,0.f}, a01 = a00, a10 = a00, a11 = a00;

  const int koff = lhi * 8;
  bf16x8 aA0 = *(const bf16x8*)&Ar0[koff];
  bf16x8 aA1 = *(const bf16x8*)&Ar1[koff];
  bf16x8 bA0 = *(const bf16x8*)&Br0[koff];
  bf16x8 bA1 = *(const bf16x8*)&Br1[koff];
  bf16x8 aB0 = *(const bf16x8*)&Ar0[32 + koff];
  bf16x8 aB1 = *(const bf16x8*)&Ar1[32 + koff];
  bf16x8 bB0 = *(const bf16x8*)&Br0[32 + koff];
  bf16x8 bB1 = *(const bf16x8*)&Br1[32 + koff];

  const int nsteps = K >> 5;  // 48
  for (int ks = 0; ks < nsteps; ks += 2) {
    const int k2 = ((ks + 2 < nsteps) ? (ks + 2) * 32 : 0) + koff;
    const int k3 = ((ks + 3 < nsteps) ? (ks + 3) * 32 : 32) + koff;
    a00 = __builtin_amdgcn_mfma_f32_16x16x32_bf16(aA0, bA0, a00, 0, 0, 0);
    a01 = __builtin_amdgcn_mfma_f32_16x16x32_bf16(aA0, bA1, a01, 0, 0, 0);
    a10 = __builtin_amdgcn_mfma_f32_16x16x32_bf16(aA1, bA0, a10, 0, 0, 0);
    a11 = __builtin_amdgcn_mfma_f32_16x16x32_bf16(aA1, bA1, a11, 0, 0, 0);
    aA0 = *(const bf16x8*)&Ar0[k2];
    aA1 = *(const bf16x8*)&Ar1[k2];
    bA0 = *(const bf16x8*)&Br0[k2];
    bA1 = *(const bf16x8*)&Br1[k2];
    a00 = __builtin_amdgcn_mfma_f32_16x16x32_bf16(aB0, bB0, a00, 0, 0, 0);
    a01 = __builtin_amdgcn_mfma_f32_16x16x32_bf16(aB0, bB1, a01, 0, 0, 0);
    a10 = __builtin_amdgcn_mfma_f32_16x16x32_bf16(aB1, bB0, a10, 0, 0, 0);
    a11 = __builtin_amdgcn_mfma_f32_16x16x32_bf16(aB1, bB1, a11, 0, 0, 0);
    aB0 = *(const bf16x8*)&Ar0[k3];
    aB1 = *(const bf16x8*)&Ar1[k3];
    bB0 = *(const bf16x8*)&Br0[k3];
    bB1 = *(const bf16x8*)&Br1[k3];
  }

  float bb[2];
#pragma unroll
  for (int ni = 0; ni < 2; ++ni) bb[ni] = bias[n0 + ni * 16 + llo];
  const f32x4 accs[2][2] = {{a00, a01}, {a10, a11}};
#pragma unroll
  for (int mi = 0; mi < 2; ++mi)
#pragma unroll
    for (int ni = 0; ni < 2; ++ni)
#pragma unroll
      for (int r = 0; r < 4; ++r) {
        int row = m0 + mi * 16 + lhi * 4 + r;
        int col = n0 + ni * 16 + llo;
        Y[(size_t)row * DD + col] = accs[mi][ni][r] + bb[ni];
      }
}

// ---------------------------------------------------------------------------
// In-block split-K flash attention. Block: 16 q-rows; wave w handles keys
// [w*512, w*512+512). Per-wave online softmax (swapped QK^T, lane-local,
// defer-max, exp2 domain); end: LDS merge of 4 partials (O, m, l), write
// split-bf16 A' rows. 4096 blocks (XCD-swizzled by bh).
__global__ __launch_bounds__(256) void attn_mfma_kernel(
    const ushort* __restrict__ Qh,  // [BH][T][DH], scaled 0.125*log2e
    const ushort* __restrict__ Kh,  // [BH][T][DH]
    const ushort* __restrict__ Vt,  // [BH][DH][T]
    const float* __restrict__ mbias,  // [B][T] 0 / -inf
    ushort* __restrict__ Ap) {        // A' [8192][1536]
  __shared__ __align__(16) ushort Plds[4][16][72];
  __shared__ __align__(16) float Ow[4][16][64];
  __shared__ float Ml[4][2][16];

  const int tid = threadIdx.x;
  const int w = tid >> 6, lane = tid & 63;
  const int lhi = lane >> 4, llo = lane & 15;

  const int bid = blockIdx.x;
  const int j = bid >> 3;
  const int bh = (bid & 7) + ((j >> 7) << 3);  // same-bh blocks -> same XCD
  const int qt = j & 127;
  const int b = bh >> 3, h = bh & 7;
  const int q0 = qt << 4;  // 16 q-rows per block

  const ushort* Qb = Qh + ((size_t)bh * TB + q0) * DH;
  const ushort* Kb = Kh + (size_t)bh * TB * DH;
  const ushort* Vb = Vt + (size_t)bh * DH * TB;
  const float* mb = mbias + b * TB;
  ushort* pl = &Plds[w][0][0];  // [16][72]

  // Q as B-fragment: col = llo = q-row, k = lhi*8 (+32 for chunk 1)
  bf16x8 qa0 = *(const bf16x8*)&Qb[llo * DH + lhi * 8];
  bf16x8 qa1 = *(const bf16x8*)&Qb[llo * DH + 32 + lhi * 8];

  f32x4 oacc[4];  // oacc[nt][r]: q-row lhi*4+r, dh = nt*16+llo
#pragma unroll
  for (int nt = 0; nt < 4; ++nt) oacc[nt] = (f32x4){0.f, 0.f, 0.f, 0.f};
  float m = -INFINITY, l = 0.f;

  const int kt0 = w << 9;
  for (int kt = kt0; kt < kt0 + 512; kt += 64) {
    // K fragments (A-frag: row = key = nt*16+llo)
    bf16x8 kf[4][2];
#pragma unroll
    for (int nt = 0; nt < 4; ++nt) {
      const ushort* kr = &Kb[(size_t)(kt + nt * 16 + llo) * DH + lhi * 8];
      kf[nt][0] = *(const bf16x8*)kr;
      kf[nt][1] = *(const bf16x8*)(kr + 32);
    }
    // mask bias, then V fragments (issued early; used at PV)
    float4 mb4[4];
#pragma unroll
    for (int nt = 0; nt < 4; ++nt)
      mb4[nt] = *(const float4*)&mb[kt + nt * 16 + lhi * 4];
    bf16x8 vf[2][4];
#pragma unroll
    for (int kc = 0; kc < 2; ++kc)
#pragma unroll
      for (int nt = 0; nt < 4; ++nt)
        vf[kc][nt] = *(const bf16x8*)
            &Vb[(size_t)(nt * 16 + llo) * TB + kt + kc * 32 + lhi * 8];

    // S^T = K Q^T
    f32x4 s[4];
    __builtin_amdgcn_s_setprio(1);
#pragma unroll
    for (int nt = 0; nt < 4; ++nt) {
      s[nt] = (f32x4){0.f, 0.f, 0.f, 0.f};
      s[nt] = __builtin_amdgcn_mfma_f32_16x16x32_bf16(kf[nt][0], qa0, s[nt], 0, 0, 0);
      s[nt] = __builtin_amdgcn_mfma_f32_16x16x32_bf16(kf[nt][1], qa1, s[nt], 0, 0, 0);
    }
    __builtin_amdgcn_s_setprio(0);

    // mask bias add (key = nt*16 + lhi*4 + r)
#pragma unroll
    for (int nt = 0; nt < 4; ++nt) {
      s[nt][0] += mb4[nt].x;
      s[nt][1] += mb4[nt].y;
      s[nt][2] += mb4[nt].z;
      s[nt][3] += mb4[nt].w;
    }

    // max over this tile for q-row llo (in-lane tree + xor16/xor32)
    float mx[4];
#pragma unroll
    for (int nt = 0; nt < 4; ++nt)
      mx[nt] = fmaxf(fmaxf(s[nt][0], s[nt][1]), fmaxf(s[nt][2], s[nt][3]));
    float pmax = fmaxf(fmaxf(mx[0], mx[1]), fmaxf(mx[2], mx[3]));
    pmax = fmaxf(pmax, __shfl_xor(pmax, 16));
    pmax = fmaxf(pmax, __shfl_xor(pmax, 32));

    // defer-max: rescale only if some row grew past m+8 (log2 units)
    if (__any(pmax > m + 8.f)) {
      float newm = fmaxf(m, pmax);        // finite (pmax > -inf here)
      float alpha = fast_exp2(m - newm);  // exp2(-inf)=0 on first tile
      float al[4];
#pragma unroll
      for (int r = 0; r < 4; ++r) al[r] = __shfl(alpha, lhi * 4 + r);
#pragma unroll
      for (int nt = 0; nt < 4; ++nt) {
        oacc[nt][0] *= al[0];
        oacc[nt][1] *= al[1];
        oacc[nt][2] *= al[2];
        oacc[nt][3] *= al[3];
      }
      l *= alpha;
      m = newm;
    }

    // p = exp2(s - m)
#pragma unroll
    for (int nt = 0; nt < 4; ++nt)
#pragma unroll
      for (int r = 0; r < 4; ++r) s[nt][r] = fast_exp2(s[nt][r] - m);
    float sm[4];
#pragma unroll
    for (int nt = 0; nt < 4; ++nt)
      sm[nt] = (s[nt][0] + s[nt][1]) + (s[nt][2] + s[nt][3]);
    float rsum = (sm[0] + sm[1]) + (sm[2] + sm[3]);
    if (__any(m == -INFINITY)) {  // dead rows so far: scrub exp2(nan)
      if (m == -INFINITY) {
        rsum = 0.f;
#pragma unroll
        for (int nt = 0; nt < 4; ++nt) s[nt] = (f32x4){0.f, 0.f, 0.f, 0.f};
      }
    }
    rsum += __shfl_xor(rsum, 16);
    rsum += __shfl_xor(rsum, 32);
    l += rsum;

    // P -> per-wave LDS (A-layout source form)
#pragma unroll
    for (int nt = 0; nt < 4; ++nt) {
      ushort4 pk;
      pk.x = f2bf(s[nt][0]);
      pk.y = f2bf(s[nt][1]);
      pk.z = f2bf(s[nt][2]);
      pk.w = f2bf(s[nt][3]);
      *(ushort4*)&pl[llo * 72 + nt * 16 + lhi * 4] = pk;
    }

    // O += P V
    __builtin_amdgcn_s_setprio(1);
#pragma unroll
    for (int kc = 0; kc < 2; ++kc) {
      bf16x8 pa = *(const bf16x8*)&pl[llo * 72 + kc * 32 + lhi * 8];
#pragma unroll
      for (int nt = 0; nt < 4; ++nt)
        oacc[nt] = __builtin_amdgcn_mfma_f32_16x16x32_bf16(pa, vf[kc][nt], oacc[nt], 0, 0, 0);
    }
    __builtin_amdgcn_s_setprio(0);
  }

  // ---- write per-wave partials, merge across waves ----
#pragma unroll
  for (int nt = 0; nt < 4; ++nt)
#pragma unroll
    for (int r = 0; r < 4; ++r)
      Ow[w][lhi * 4 + r][nt * 16 + llo] = oacc[nt][r];
  if (lane < 16) {
    Ml[w][0][llo] = m;
    Ml[w][1][llo] = l;
  }
  __syncthreads();

  const int q = tid >> 4;           // 0..15
  const int d4 = (tid & 15) << 2;   // 0..60
  float m0 = Ml[0][0][q], m1 = Ml[1][0][q], m2 = Ml[2][0][q], m3 = Ml[3][0][q];
  float M = fmaxf(fmaxf(m0, m1), fmaxf(m2, m3));
  ushort4 h4 = {0, 0, 0, 0}, l4 = {0, 0, 0, 0};
  if (M != -INFINITY) {
    float e0 = fast_exp2(m0 - M), e1 = fast_exp2(m1 - M);
    float e2 = fast_exp2(m2 - M), e3 = fast_exp2(m3 - M);
    float den = Ml[0][1][q] * e0 + Ml[1][1][q] * e1 +
                Ml[2][1][q] * e2 + Ml[3][1][q] * e3;
    float4 o0 = *(const float4*)&Ow[0][q][d4];
    float4 o1 = *(const float4*)&Ow[1][q][d4];
    float4 o2 = *(const float4*)&Ow[2][q][d4];
    float4 o3 = *(const float4*)&Ow[3][q][d4];
    float inv = (den > 0.f) ? 1.f / den : 0.f;
    float ox = (o0.x * e0 + o1.x * e1 + o2.x * e2 + o3.x * e3) * inv;
    float oy = (o0.y * e0 + o1.y * e1 + o2.y * e2 + o3.y * e3) * inv;
    float oz = (o0.z * e0 + o1.z * e1 + o2.z * e2 + o3.z * e3) * inv;
    float ow = (o0.w * e0 + o1.w * e1 + o2.w * e2 + o3.w * e3) * inv;
    h4.x = f2bf(ox); l4.x = f2bf(ox - bf2f(h4.x));
    h4.y = f2bf(oy); l4.y = f2bf(oy - bf2f(h4.y));
    h4.z = f2bf(oz); l4.z = f2bf(oz - bf2f(h4.z));
    h4.w = f2bf(ow); l4.w = f2bf(ow - bf2f(h4.w));
  }
  size_t rowb = (size_t)(b * TB + q0 + q) * 1536;
  int c = h * DH + d4;
  *(ushort4*)&Ap[rowb + c] = h4;
  *(ushort4*)&Ap[rowb + 512 + c] = l4;
  *(ushort4*)&Ap[rowb + 1024 + c] = h4;
}

// ---------------------------------------------------------------------------
extern "C" void kernel_launch(void* const* d_in, const int* in_sizes, int n_in,
                              void* d_out, int out_size, void* d_ws,
                              size_t ws_size, hipStream_t stream) {
  (void)in_sizes; (void)n_in; (void)out_size; (void)ws_size;
  const float* q = (const float*)d_in[0];
  const float* k = (const float*)d_in[1];
  const float* v = (const float*)d_in[2];
  const void* pm = d_in[3];
  const float* Wq = (const float*)d_in[4];
  const float* bq = (const float*)d_in[5];
  const float* Wk = (const float*)d_in[6];
  const float* bk = (const float*)d_in[7];
  const float* Wv = (const float*)d_in[8];
  const float* bv = (const float*)d_in[9];
  const float* Wo = (const float*)d_in[10];
  const float* bo = (const float*)d_in[11];

  char* ws = (char*)d_ws;
  const size_t MB = (size_t)1 << 20;
  // [0,24MB): bf16 inputs (dead after projs) -> reused as A' (attn out, 24MB)
  ushort* Qb16 = (ushort*)(ws);
  ushort* Kb16 = (ushort*)(ws + 8 * MB);
  ushort* Vb16 = (ushort*)(ws + 16 * MB);
  ushort* Ap = (ushort*)(ws);  // 8192*1536*2 = 24MB
  // [24,25.5MB): Wall = [Wq^T | Wk^T | Wv^T] bf16 (contiguous, 512KB each)
  ushort* Wall = (ushort*)(ws + 24 * MB);
  // [26,27.5MB): split O-weight
  ushort* Wot = (ushort*)(ws + 26 * MB);
  // [32,56MB): projected heads (contiguous 8MB sections: Qh, Kh, Vt)
  ushort* Qh = (ushort*)(ws + 32 * MB);
  ushort* Kh = (ushort*)(ws + 40 * MB);
  ushort* Vt = (ushort*)(ws + 48 * MB);
  float* mbias = (float*)(ws + 56 * MB);
  int* mode = (int*)(ws + 56 * MB + 40960);

  mask_detect_kernel<<<1, 256, 0, stream>>>((const unsigned char*)pm, mode);
  mask_build_kernel<<<32, 256, 0, stream>>>(pm, mode, mbias);

  cvt_kernel<<<2048, 256, 0, stream>>>(q, Qb16);
  cvt_kernel<<<2048, 256, 0, stream>>>(k, Kb16);
  cvt_kernel<<<2048, 256, 0, stream>>>(v, Vb16);
  wtrans_kernel<<<dim3(8, 8), 256, 0, stream>>>(Wq, Wall);
  wtrans_kernel<<<dim3(8, 8), 256, 0, stream>>>(Wk, Wall + (512 * 512));
  wtrans_kernel<<<dim3(8, 8), 256, 0, stream>>>(Wv, Wall + (2 * 512 * 512));
  wtrans_split_kernel<<<dim3(8, 8), 256, 0, stream>>>(Wo, Wot);

  // Q scale folds 1/sqrt(64) * log2(e) for the exp2-domain softmax
  const float qscale = 0.125f * 1.4426950408889634f;
  projqkv_kernel<<<dim3(256, 48), 64, 0, stream>>>(Qb16, Kb16, Vb16, Wall,
                                                   bq, bk, bv, Qh, qscale);

  attn_mfma_kernel<<<4096, 256, 0, stream>>>(Qh, Kh, Vt, mbias, Ap);

  projo_kernel<<<dim3(256, 16), 64, 0, stream>>>(Ap, Wot, bo, (float*)d_out);
}

// Round 8
// 304.919 us; speedup vs baseline: 1.5534x; 1.5237x over previous
//
#include <hip/hip_runtime.h>
#include <hip/hip_bf16.h>
#include <math.h>

// MultiHeadAttention  B=4, T=2048, D=512, H=8, DH=64, fp32 in/out.
// R8 (= R7 resubmit after container failure): fragment-linear Q/K/V global
// layouts (producer scatters into MFMA fragment order; consumer loads =
// contiguous 1KB bursts at base+imm), v_perm_b32 P-packing, R5 block shape
// (64q x 4 waves, 9KB LDS).

#define TB 2048
#define DD 512
#define NH 8
#define DH 64

typedef short bf16x8 __attribute__((ext_vector_type(8)));
typedef float f32x4 __attribute__((ext_vector_type(4)));
typedef ushort u16x8 __attribute__((ext_vector_type(8)));

static __device__ __forceinline__ ushort f2bf(float x) {
  __hip_bfloat16 h = __float2bfloat16(x);
  return *reinterpret_cast<ushort*>(&h);
}
static __device__ __forceinline__ float bf2f(ushort u) {
  unsigned int v = ((unsigned int)u) << 16;
  return __uint_as_float(v);
}
static __device__ __forceinline__ float fast_exp2(float x) {
  return __builtin_amdgcn_exp2f(x);  // v_exp_f32: D = 2^S0
}

// ---------------------------------------------------------------------------
// Mask canonicalization (verified R1-R6). Output: float bias 0 / -inf.
__global__ void mask_detect_kernel(const unsigned char* __restrict__ m,
                                   int* __restrict__ mode) {
  __shared__ int c1, c2;
  if (threadIdx.x == 0) { c1 = 0; c2 = 0; }
  __syncthreads();
  int l1 = 0, l2 = 0;
  for (int i = threadIdx.x; i < 8192; i += blockDim.x) {
    int ph = i & 3;
    unsigned char v = m[i];
    if (ph == 1 && v) l1++;
    if (ph == 2 && v) l2++;
  }
  if (l1) atomicAdd(&c1, l1);
  if (l2) atomicAdd(&c2, l2);
  __syncthreads();
  if (threadIdx.x == 0) *mode = (c1 > 0) ? 0 : ((c2 > 0) ? 1 : 2);
}

__global__ void mask_build_kernel(const void* __restrict__ m,
                                  const int* __restrict__ mode,
                                  float* __restrict__ out) {
  int i = blockIdx.x * blockDim.x + threadIdx.x;
  int md = *mode;
  int v;
  if (md == 0)      v = ((const unsigned char*)m)[i] != 0;
  else if (md == 1) v = ((const float*)m)[i] != 0.0f;
  else              v = ((const int*)m)[i] != 0;
  out[i] = v ? 0.0f : -INFINITY;
}

// ---------------------------------------------------------------------------
// fp32 -> bf16 bulk convert.
__global__ __launch_bounds__(256) void cvt_kernel(const float* __restrict__ in,
                                                  ushort* __restrict__ out) {
  size_t i = ((size_t)blockIdx.x * 256 + threadIdx.x) * 8;
  float4 a = *(const float4*)&in[i];
  float4 b = *(const float4*)&in[i + 4];
  u16x8 o;
  o[0] = f2bf(a.x); o[1] = f2bf(a.y); o[2] = f2bf(a.z); o[3] = f2bf(a.w);
  o[4] = f2bf(b.x); o[5] = f2bf(b.y); o[6] = f2bf(b.z); o[7] = f2bf(b.w);
  *(u16x8*)&out[i] = o;
}

// ---------------------------------------------------------------------------
// W [K][N] f32 -> Wt [N][K] bf16.
__global__ __launch_bounds__(256) void wtrans_kernel(const float* __restrict__ W,
                                                     ushort* __restrict__ Wt) {
  __shared__ ushort t[64][68];
  const int bn = blockIdx.x << 6, bk = blockIdx.y << 6;
  const int tx = threadIdx.x & 15, ty = threadIdx.x >> 4;
#pragma unroll
  for (int rr = 0; rr < 64; rr += 16) {
    float4 v = *(const float4*)&W[(size_t)(bk + rr + ty) * DD + bn + (tx << 2)];
    t[(tx << 2) + 0][rr + ty] = f2bf(v.x);
    t[(tx << 2) + 1][rr + ty] = f2bf(v.y);
    t[(tx << 2) + 2][rr + ty] = f2bf(v.z);
    t[(tx << 2) + 3][rr + ty] = f2bf(v.w);
  }
  __syncthreads();
#pragma unroll
  for (int rr = 0; rr < 64; rr += 16) {
    ushort4 o;
    o.x = t[rr + ty][(tx << 2) + 0];
    o.y = t[rr + ty][(tx << 2) + 1];
    o.z = t[rr + ty][(tx << 2) + 2];
    o.w = t[rr + ty][(tx << 2) + 3];
    *(ushort4*)&Wt[(size_t)(bn + rr + ty) * DD + bk + (tx << 2)] = o;
  }
}

// ---------------------------------------------------------------------------
// Wo [K][N] f32 -> Wt' [N][1536]: sections [Whi | Whi | Wlo] (split-bf16).
__global__ __launch_bounds__(256) void wtrans_split_kernel(
    const float* __restrict__ W, ushort* __restrict__ Wt) {
  __shared__ ushort thi[64][68];
  __shared__ ushort tlo[64][68];
  const int bn = blockIdx.x << 6, bk = blockIdx.y << 6;
  const int tx = threadIdx.x & 15, ty = threadIdx.x >> 4;
#pragma unroll
  for (int rr = 0; rr < 64; rr += 16) {
    float4 v = *(const float4*)&W[(size_t)(bk + rr + ty) * DD + bn + (tx << 2)];
    float vv[4] = {v.x, v.y, v.z, v.w};
#pragma unroll
    for (int c = 0; c < 4; ++c) {
      ushort hi = f2bf(vv[c]);
      ushort lo = f2bf(vv[c] - bf2f(hi));
      thi[(tx << 2) + c][rr + ty] = hi;
      tlo[(tx << 2) + c][rr + ty] = lo;
    }
  }
  __syncthreads();
#pragma unroll
  for (int rr = 0; rr < 64; rr += 16) {
    ushort4 h4, l4;
    h4.x = thi[rr + ty][(tx << 2) + 0];
    h4.y = thi[rr + ty][(tx << 2) + 1];
    h4.z = thi[rr + ty][(tx << 2) + 2];
    h4.w = thi[rr + ty][(tx << 2) + 3];
    l4.x = tlo[rr + ty][(tx << 2) + 0];
    l4.y = tlo[rr + ty][(tx << 2) + 1];
    l4.z = tlo[rr + ty][(tx << 2) + 2];
    l4.w = tlo[rr + ty][(tx << 2) + 3];
    size_t rowb = (size_t)(bn + rr + ty) * 1536;
    *(ushort4*)&Wt[rowb + bk + (tx << 2)] = h4;         // sec0: Whi
    *(ushort4*)&Wt[rowb + 512 + bk + (tx << 2)] = h4;   // sec1: Whi
    *(ushort4*)&Wt[rowb + 1024 + bk + (tx << 2)] = l4;  // sec2: Wlo
  }
}

// ---------------------------------------------------------------------------
// Fused QKV projection -> fragment-linear outputs.
// Q: [bh][qt16][c][lane][8]   (qt16=t>>4, llo=t&15; c=dh>>5, lhi=(dh>>3)&3)
// K: [bh][kt64][c*4+nt][lane][8]  (kt64=t>>6, nt=(t>>4)&3, llo=t&15)
// V: [bh][kt64][kc*4+nt][lane][8] (kc=(t>>5)&1, lhi=(t>>3)&3, e=t&7 from t;
//                                  nt=dh>>4, llo=dh&15 from dh)
__global__ __launch_bounds__(64) void projqkv_kernel(
    const ushort* __restrict__ Qx, const ushort* __restrict__ Kx,
    const ushort* __restrict__ Vx, const ushort* __restrict__ Wall,
    const float* __restrict__ bq, const float* __restrict__ bk,
    const float* __restrict__ bv, ushort* __restrict__ Yall, float qscale) {
  const int lane = threadIdx.x, llo = lane & 15, lhi = lane >> 4;
  const int m0 = blockIdx.x << 5;
  const int ny = blockIdx.y;
  const int sec = ny >> 4;          // 0=Q, 1=K, 2=V
  const int n0 = (ny << 5) & 511;   // within-section col base

  const ushort* A = (sec == 0) ? Qx : (sec == 1) ? Kx : Vx;
  const float* bias = (sec == 0) ? bq : (sec == 1) ? bk : bv;
  const float scale = (sec == 0) ? qscale : 1.0f;

  const ushort* Ar0 = A + (size_t)(m0 + llo) * DD;
  const ushort* Ar1 = Ar0 + (size_t)16 * DD;
  const ushort* Br0 = Wall + (size_t)(ny * 32 + llo) * DD;
  const ushort* Br1 = Br0 + (size_t)16 * DD;

  f32x4 a00 = {0.f,0.f,0.f,0.f}, a01 = a00, a10 = a00, a11 = a00;

  const int koff = lhi * 8;
  bf16x8 aA0 = *(const bf16x8*)&Ar0[koff];
  bf16x8 aA1 = *(const bf16x8*)&Ar1[koff];
  bf16x8 bA0 = *(const bf16x8*)&Br0[koff];
  bf16x8 bA1 = *(const bf16x8*)&Br1[koff];
  bf16x8 aB0 = *(const bf16x8*)&Ar0[32 + koff];
  bf16x8 aB1 = *(const bf16x8*)&Ar1[32 + koff];
  bf16x8 bB0 = *(const bf16x8*)&Br0[32 + koff];
  bf16x8 bB1 = *(const bf16x8*)&Br1[32 + koff];

  const int nsteps = DD >> 5;  // 16
#pragma unroll 2
  for (int ks = 0; ks < nsteps; ks += 2) {
    const int k2 = ((ks + 2 < nsteps) ? (ks + 2) * 32 : 0) + koff;
    const int k3 = ((ks + 3 < nsteps) ? (ks + 3) * 32 : 32) + koff;
    a00 = __builtin_amdgcn_mfma_f32_16x16x32_bf16(aA0, bA0, a00, 0, 0, 0);
    a01 = __builtin_amdgcn_mfma_f32_16x16x32_bf16(aA0, bA1, a01, 0, 0, 0);
    a10 = __builtin_amdgcn_mfma_f32_16x16x32_bf16(aA1, bA0, a10, 0, 0, 0);
    a11 = __builtin_amdgcn_mfma_f32_16x16x32_bf16(aA1, bA1, a11, 0, 0, 0);
    aA0 = *(const bf16x8*)&Ar0[k2];
    aA1 = *(const bf16x8*)&Ar1[k2];
    bA0 = *(const bf16x8*)&Br0[k2];
    bA1 = *(const bf16x8*)&Br1[k2];
    a00 = __builtin_amdgcn_mfma_f32_16x16x32_bf16(aB0, bB0, a00, 0, 0, 0);
    a01 = __builtin_amdgcn_mfma_f32_16x16x32_bf16(aB0, bB1, a01, 0, 0, 0);
    a10 = __builtin_amdgcn_mfma_f32_16x16x32_bf16(aB1, bB0, a10, 0, 0, 0);
    a11 = __builtin_amdgcn_mfma_f32_16x16x32_bf16(aB1, bB1, a11, 0, 0, 0);
    aB0 = *(const bf16x8*)&Ar0[k3];
    aB1 = *(const bf16x8*)&Ar1[k3];
    bB0 = *(const bf16x8*)&Br0[k3];
    bB1 = *(const bf16x8*)&Br1[k3];
  }

  float bb[2];
#pragma unroll
  for (int ni = 0; ni < 2; ++ni) bb[ni] = bias[n0 + ni * 16 + llo];

  ushort* Yq = Yall;
  ushort* Yk = Yall + ((size_t)4 << 20);
  ushort* Yv = Yall + ((size_t)8 << 20);
  const f32x4 accs[2][2] = {{a00, a01}, {a10, a11}};
#pragma unroll
  for (int mi = 0; mi < 2; ++mi)
#pragma unroll
    for (int ni = 0; ni < 2; ++ni) {
      int col = n0 + ni * 16 + llo;
      int h = col >> 6, dh = col & (DH - 1);
#pragma unroll
      for (int r = 0; r < 4; ++r) {
        int row = m0 + mi * 16 + lhi * 4 + r;
        int bidx = row >> 11, t = row & (TB - 1);
        int bh = bidx * NH + h;
        ushort u = f2bf((accs[mi][ni][r] + bb[ni]) * scale);
        if (sec == 0) {
          Yq[((size_t)(bh * 128 + (t >> 4)) * 2 + (dh >> 5)) * 512 +
             ((((dh >> 3) & 3) << 4) + (t & 15)) * 8 + (dh & 7)] = u;
        } else if (sec == 1) {
          Yk[((size_t)(bh * 32 + (t >> 6)) << 12) +
             (((dh >> 5) << 2) + ((t >> 4) & 3)) * 512 +
             ((((dh >> 3) & 3) << 4) + (t & 15)) * 8 + (dh & 7)] = u;
        } else {
          Yv[((size_t)(bh * 32 + (t >> 6)) << 12) +
             ((((t >> 5) & 1) << 2) + (dh >> 4)) * 512 +
             ((((t >> 3) & 3) << 4) + (dh & 15)) * 8 + (t & 7)] = u;
        }
      }
    }
}

// ---------------------------------------------------------------------------
// O-projection: A' [8192][1536] split-bf16 @ Wot [512][1536] -> f32 + bias.
__global__ __launch_bounds__(64) void projo_kernel(
    const ushort* __restrict__ A, const ushort* __restrict__ Wt,
    const float* __restrict__ bias, float* __restrict__ Y) {
  const int lane = threadIdx.x, llo = lane & 15, lhi = lane >> 4;
  const int m0 = blockIdx.x << 5, n0 = blockIdx.y << 5;
  const int K = 1536;
  const ushort* Ar0 = A + (size_t)(m0 + llo) * K;
  const ushort* Ar1 = Ar0 + (size_t)16 * K;
  const ushort* Br0 = Wt + (size_t)(n0 + llo) * K;
  const ushort* Br1 = Br0 + (size_t)16 * K;

  f32x4 a00 = {0.f,0.f,0.f,0.f}, a01 = a00, a10 = a00, a11 = a00;

  const int koff = lhi * 8;
  bf16x8 aA0 = *(const bf16x8*)&Ar0[koff];
  bf16x8 aA1 = *(const bf16x8*)&Ar1[koff];
  bf16x8 bA0 = *(const bf16x8*)&Br0[koff];
  bf16x8 bA1 = *(const bf16x8*)&Br1[koff];
  bf16x8 aB0 = *(const bf16x8*)&Ar0[32 + koff];
  bf16x8 aB1 = *(const bf16x8*)&Ar1[32 + koff];
  bf16x8 bB0 = *(const bf16x8*)&Br0[32 + koff];
  bf16x8 bB1 = *(const bf16x8*)&Br1[32 + koff];

  const int nsteps = K >> 5;  // 48
  for (int ks = 0; ks < nsteps; ks += 2) {
    const int k2 = ((ks + 2 < nsteps) ? (ks + 2) * 32 : 0) + koff;
    const int k3 = ((ks + 3 < nsteps) ? (ks + 3) * 32 : 32) + koff;
    a00 = __builtin_amdgcn_mfma_f32_16x16x32_bf16(aA0, bA0, a00, 0, 0, 0);
    a01 = __builtin_amdgcn_mfma_f32_16x16x32_bf16(aA0, bA1, a01, 0, 0, 0);
    a10 = __builtin_amdgcn_mfma_f32_16x16x32_bf16(aA1, bA0, a10, 0, 0, 0);
    a11 = __builtin_amdgcn_mfma_f32_16x16x32_bf16(aA1, bA1, a11, 0, 0, 0);
    aA0 = *(const bf16x8*)&Ar0[k2];
    aA1 = *(const bf16x8*)&Ar1[k2];
    bA0 = *(const bf16x8*)&Br0[k2];
    bA1 = *(const bf16x8*)&Br1[k2];
    a00 = __builtin_amdgcn_mfma_f32_16x16x32_bf16(aB0, bB0, a00, 0, 0, 0);
    a01 = __builtin_amdgcn_mfma_f32_16x16x32_bf16(aB0, bB1, a01, 0, 0, 0);
    a10 = __builtin_amdgcn_mfma_f32_16x16x32_bf16(aB1, bB0, a10, 0, 0, 0);
    a11 = __builtin_amdgcn_mfma_f32_16x16x32_bf16(aB1, bB1, a11, 0, 0, 0);
    aB0 = *(const bf16x8*)&Ar0[k3];
    aB1 = *(const bf16x8*)&Ar1[k3];
    bB0 = *(const bf16x8*)&Br0[k3];
    bB1 = *(const bf16x8*)&Br1[k3];
  }

  float bb[2];
#pragma unroll
  for (int ni = 0; ni < 2; ++ni) bb[ni] = bias[n0 + ni * 16 + llo];
  const f32x4 accs[2][2] = {{a00, a01}, {a10, a11}};
#pragma unroll
  for (int mi = 0; mi < 2; ++mi)
#pragma unroll
    for (int ni = 0; ni < 2; ++ni)
#pragma unroll
      for (int r = 0; r < 4; ++r) {
        int row = m0 + mi * 16 + lhi * 4 + r;
        int col = n0 + ni * 16 + llo;
        Y[(size_t)row * DD + col] = accs[mi][ni][r] + bb[ni];
      }
}

// ---------------------------------------------------------------------------
// Swapped-QK^T bf16 MFMA flash attention, fragment-linear operands.
// Block: 64 q-rows, 4 waves x 16 q-rows; full 2048-key scan.
// Per tile: 8 K loads + 8 V loads, each contiguous 1KB at base+imm.
__global__ __launch_bounds__(256) void attn_mfma_kernel(
    const ushort* __restrict__ Qf,    // frag-linear, scaled 0.125*log2e
    const ushort* __restrict__ Kf,    // frag-linear
    const ushort* __restrict__ Vf,    // frag-linear (V^T frags)
    const float* __restrict__ mbias,  // [B][T] 0 / -inf
    ushort* __restrict__ Ap) {        // A' [8192][1536]
  __shared__ __align__(16) ushort Plds[4][16][72];

  const int tid = threadIdx.x;
  const int w = tid >> 6, lane = tid & 63;
  const int lhi = lane >> 4, llo = lane & 15;
  const int lane8 = lane * 8;

  const int bid = blockIdx.x;
  const int j = bid >> 3;
  const int bh = (bid & 7) + ((j >> 5) << 3);  // same-bh blocks -> same XCD
  const int qt = j & 31;
  const int b = bh >> 3, h = bh & 7;
  const int q0 = qt << 6;

  const float* mb = mbias + b * TB;
  ushort* pl = &Plds[w][0][0];  // [16][72]

  // Q fragments (one 1KB tile per wave: qt16 = q0/16 + w)
  const ushort* Qb = Qf + ((size_t)((bh << 7) + (q0 >> 4) + w) * 2) * 512 + lane8;
  bf16x8 qa0 = *(const bf16x8*)Qb;
  bf16x8 qa1 = *(const bf16x8*)(Qb + 512);

  const size_t bhK = (size_t)bh << 5;  // bh*32 tiles
  f32x4 oacc[4];  // oacc[nt][r]: q-row lhi*4+r, dh = nt*16+llo
#pragma unroll
  for (int nt = 0; nt < 4; ++nt) oacc[nt] = (f32x4){0.f, 0.f, 0.f, 0.f};
  float m = -INFINITY, l = 0.f;

  for (int kt64 = 0; kt64 < 32; ++kt64) {
    const ushort* Kt = Kf + ((bhK + kt64) << 12) + lane8;
    const ushort* Vt = Vf + ((bhK + kt64) << 12) + lane8;
    // K fragments: i = c*4+nt (c = dh chunk)
    bf16x8 kf[8];
#pragma unroll
    for (int i = 0; i < 8; ++i) kf[i] = *(const bf16x8*)(Kt + i * 512);
    // V fragments (early-issue; used at PV): i = kc*4+nt
    bf16x8 vf[8];
#pragma unroll
    for (int i = 0; i < 8; ++i) vf[i] = *(const bf16x8*)(Vt + i * 512);
    float4 mb4[4];
#pragma unroll
    for (int nt = 0; nt < 4; ++nt)
      mb4[nt] = *(const float4*)&mb[kt64 * 64 + nt * 16 + lhi * 4];

    // S^T = K Q^T  (s[nt][r]: key = nt*16+lhi*4+r, q-row = llo)
    f32x4 s[4];
    __builtin_amdgcn_s_setprio(1);
#pragma unroll
    for (int nt = 0; nt < 4; ++nt) {
      s[nt] = (f32x4){0.f, 0.f, 0.f, 0.f};
      s[nt] = __builtin_amdgcn_mfma_f32_16x16x32_bf16(kf[nt], qa0, s[nt], 0, 0, 0);
      s[nt] = __builtin_amdgcn_mfma_f32_16x16x32_bf16(kf[4 + nt], qa1, s[nt], 0, 0, 0);
    }
    __builtin_amdgcn_s_setprio(0);

    // mask bias add
#pragma unroll
    for (int nt = 0; nt < 4; ++nt) {
      s[nt][0] += mb4[nt].x;
      s[nt][1] += mb4[nt].y;
      s[nt][2] += mb4[nt].z;
      s[nt][3] += mb4[nt].w;
    }

    // row max (in-lane tree + xor16/xor32)
    float mx[4];
#pragma unroll
    for (int nt = 0; nt < 4; ++nt)
      mx[nt] = fmaxf(fmaxf(s[nt][0], s[nt][1]), fmaxf(s[nt][2], s[nt][3]));
    float pmax = fmaxf(fmaxf(mx[0], mx[1]), fmaxf(mx[2], mx[3]));
    pmax = fmaxf(pmax, __shfl_xor(pmax, 16));
    pmax = fmaxf(pmax, __shfl_xor(pmax, 32));

    // defer-max: rescale only if some row grew past m+8 (log2 units)
    if (__any(pmax > m + 8.f)) {
      float newm = fmaxf(m, pmax);
      float alpha = fast_exp2(m - newm);
      float al[4];
#pragma unroll
      for (int r = 0; r < 4; ++r) al[r] = __shfl(alpha, lhi * 4 + r);
#pragma unroll
      for (int nt = 0; nt < 4; ++nt) {
        oacc[nt][0] *= al[0];
        oacc[nt][1] *= al[1];
        oacc[nt][2] *= al[2];
        oacc[nt][3] *= al[3];
      }
      l *= alpha;
      m = newm;
    }

    // p = exp2(s - m)
#pragma unroll
    for (int nt = 0; nt < 4; ++nt)
#pragma unroll
      for (int r = 0; r < 4; ++r) s[nt][r] = fast_exp2(s[nt][r] - m);
    float sm[4];
#pragma unroll
    for (int nt = 0; nt < 4; ++nt)
      sm[nt] = (s[nt][0] + s[nt][1]) + (s[nt][2] + s[nt][3]);
    float rsum = (sm[0] + sm[1]) + (sm[2] + sm[3]);
    if (__any(m == -INFINITY)) {  // dead rows so far: scrub exp2(nan)
      if (m == -INFINITY) {
        rsum = 0.f;
#pragma unroll
        for (int nt = 0; nt < 4; ++nt) s[nt] = (f32x4){0.f, 0.f, 0.f, 0.f};
      }
    }
    rsum += __shfl_xor(rsum, 16);
    rsum += __shfl_xor(rsum, 32);
    l += rsum;

    // P pack (round-half-up via +0x8000, v_perm packs 2 f32 -> 2 bf16)
#pragma unroll
    for (int nt = 0; nt < 4; ++nt) {
      unsigned int lo = __builtin_amdgcn_perm(
          __float_as_uint(s[nt][1]) + 0x8000u,
          __float_as_uint(s[nt][0]) + 0x8000u, 0x07060302u);
      unsigned int hi = __builtin_amdgcn_perm(
          __float_as_uint(s[nt][3]) + 0x8000u,
          __float_as_uint(s[nt][2]) + 0x8000u, 0x07060302u);
      *(uint2*)&pl[llo * 72 + nt * 16 + lhi * 4] = make_uint2(lo, hi);
    }

    // O += P V
    __builtin_amdgcn_s_setprio(1);
#pragma unroll
    for (int kc = 0; kc < 2; ++kc) {
      bf16x8 pa = *(const bf16x8*)&pl[llo * 72 + kc * 32 + lhi * 8];
#pragma unroll
      for (int nt = 0; nt < 4; ++nt)
        oacc[nt] = __builtin_amdgcn_mfma_f32_16x16x32_bf16(pa, vf[kc * 4 + nt], oacc[nt], 0, 0, 0);
    }
    __builtin_amdgcn_s_setprio(0);
  }

  // epilogue: normalize rows, write split-bf16 A' = [hi | lo | hi]
  float linv = (l > 0.f) ? 1.f / l : 0.f;
  float il[4];
#pragma unroll
  for (int r = 0; r < 4; ++r) il[r] = __shfl(linv, lhi * 4 + r);
  const int t0 = q0 + w * 16 + lhi * 4;
#pragma unroll
  for (int r = 0; r < 4; ++r) {
    size_t rowb = (size_t)(b * TB + t0 + r) * 1536;
#pragma unroll
    for (int nt = 0; nt < 4; ++nt) {
      float o = oacc[nt][r] * il[r];
      ushort hi = f2bf(o);
      ushort lo = f2bf(o - bf2f(hi));
      int c = h * DH + nt * 16 + llo;
      Ap[rowb + c] = hi;
      Ap[rowb + 512 + c] = lo;
      Ap[rowb + 1024 + c] = hi;
    }
  }
}

// ---------------------------------------------------------------------------
extern "C" void kernel_launch(void* const* d_in, const int* in_sizes, int n_in,
                              void* d_out, int out_size, void* d_ws,
                              size_t ws_size, hipStream_t stream) {
  (void)in_sizes; (void)n_in; (void)out_size; (void)ws_size;
  const float* q = (const float*)d_in[0];
  const float* k = (const float*)d_in[1];
  const float* v = (const float*)d_in[2];
  const void* pm = d_in[3];
  const float* Wq = (const float*)d_in[4];
  const float* bq = (const float*)d_in[5];
  const float* Wk = (const float*)d_in[6];
  const float* bk = (const float*)d_in[7];
  const float* Wv = (const float*)d_in[8];
  const float* bv = (const float*)d_in[9];
  const float* Wo = (const float*)d_in[10];
  const float* bo = (const float*)d_in[11];

  char* ws = (char*)d_ws;
  const size_t MB = (size_t)1 << 20;
  // [0,24MB): bf16 inputs (dead after projs) -> reused as A' (attn out, 24MB)
  ushort* Qb16 = (ushort*)(ws);
  ushort* Kb16 = (ushort*)(ws + 8 * MB);
  ushort* Vb16 = (ushort*)(ws + 16 * MB);
  ushort* Ap = (ushort*)(ws);  // 8192*1536*2 = 24MB
  // [24,25.5MB): Wall = [Wq^T | Wk^T | Wv^T] bf16
  ushort* Wall = (ushort*)(ws + 24 * MB);
  // [26,27.5MB): split O-weight
  ushort* Wot = (ushort*)(ws + 26 * MB);
  // [32,56MB): fragment-linear Q/K/V (8MB sections)
  ushort* Qh = (ushort*)(ws + 32 * MB);
  float* mbias = (float*)(ws + 56 * MB);
  int* mode = (int*)(ws + 56 * MB + 40960);

  mask_detect_kernel<<<1, 256, 0, stream>>>((const unsigned char*)pm, mode);
  mask_build_kernel<<<32, 256, 0, stream>>>(pm, mode, mbias);

  cvt_kernel<<<2048, 256, 0, stream>>>(q, Qb16);
  cvt_kernel<<<2048, 256, 0, stream>>>(k, Kb16);
  cvt_kernel<<<2048, 256, 0, stream>>>(v, Vb16);
  wtrans_kernel<<<dim3(8, 8), 256, 0, stream>>>(Wq, Wall);
  wtrans_kernel<<<dim3(8, 8), 256, 0, stream>>>(Wk, Wall + (512 * 512));
  wtrans_kernel<<<dim3(8, 8), 256, 0, stream>>>(Wv, Wall + (2 * 512 * 512));
  wtrans_split_kernel<<<dim3(8, 8), 256, 0, stream>>>(Wo, Wot);

  // Q scale folds 1/sqrt(64) * log2(e) for the exp2-domain softmax
  const float qscale = 0.125f * 1.4426950408889634f;
  projqkv_kernel<<<dim3(256, 48), 64, 0, stream>>>(Qb16, Kb16, Vb16, Wall,
                                                   bq, bk, bv, Qh, qscale);

  attn_mfma_kernel<<<1024, 256, 0, stream>>>(
      Qh, Qh + ((size_t)4 << 20), Qh + ((size_t)8 << 20), mbias, Ap);

  projo_kernel<<<dim3(256, 16), 64, 0, stream>>>(Ap, Wot, bo, (float*)d_out);
}